// Round 1
// 571.838 us; speedup vs baseline: 1.0057x; 1.0057x over previous
//
#include <hip/hip_runtime.h>
#include <hip/hip_bf16.h>
#include <cstdint>

#define S_LEN 2304
#define NDIM  3072
#define NH    24
#define HD    128

typedef unsigned short u16;
typedef __bf16  bf16x8  __attribute__((ext_vector_type(8)));
typedef float   floatx4 __attribute__((ext_vector_type(4)));

__device__ __forceinline__ u16 f2bf(float x) {
  union { float f; unsigned int u; } a; a.f = x;
  unsigned int r = (a.u + 0x7FFFu + ((a.u >> 16) & 1u)) >> 16;
  return (u16)r;
}

// async 16B global->LDS (direct-to-shared DMA). LDS dest must be
// wave-uniform base + lane*16 -- all call sites arrange that.
__device__ __forceinline__ void async_load16(const void* g, void* l) {
  auto gp = (const __attribute__((address_space(1))) unsigned int*)(unsigned long long)(g);
  auto lp = (__attribute__((address_space(3))) unsigned int*)(unsigned int)(unsigned long long)(l);
  __builtin_amdgcn_global_load_lds(gp, lp, 16, 0, 0);
}

// ------------------------------------------- fp32->bf16, all 5 tensors fused
__global__ __launch_bounds__(256) void cvt_all(const float* __restrict__ x,
                                               const float* __restrict__ w0,
                                               const float* __restrict__ w1,
                                               const float* __restrict__ w2,
                                               const float* __restrict__ w3,
                                               u16* __restrict__ xo,
                                               u16* __restrict__ o0,
                                               u16* __restrict__ o1,
                                               u16* __restrict__ o2,
                                               u16* __restrict__ o3) {
  long b = blockIdx.x;
  const float* in; u16* out;
  if (b < 3456) { in = x; out = xo; }
  else {
    long wi = (b - 3456) / 4608;
    b = (b - 3456) % 4608;
    in  = (wi == 0) ? w0 : (wi == 1) ? w1 : (wi == 2) ? w2 : w3;
    out = (wi == 0) ? o0 : (wi == 1) ? o1 : (wi == 2) ? o2 : o3;
  }
  long i = (b * 256 + threadIdx.x) * 8;
  float4 a = *(const float4*)(in + i);
  float4 c = *(const float4*)(in + i + 4);
  union { u16 h[8]; uint4 u; } r;
  r.h[0] = f2bf(a.x); r.h[1] = f2bf(a.y); r.h[2] = f2bf(a.z); r.h[3] = f2bf(a.w);
  r.h[4] = f2bf(c.x); r.h[5] = f2bf(c.y); r.h[6] = f2bf(c.z); r.h[7] = f2bf(c.w);
  *(uint4*)(out + i) = r.u;
}

// ---------------------------------------------------------------- GEMM core
// C[M,N] = A[M,K] @ B[N,K]^T.  A,B bf16; acc fp32.
// 256x128 tile, BK=64, 512 threads = 8 waves (4M x 2N), per-wave 64x64.
// Pipelined: raw s_barrier pair + counted vmcnt(6) -- next tile's 6
// global_load_lds stay in flight across the barriers (no vmcnt(0) drain).
//   B1: all waves finished reading buf cur^1 (prev iter)  -> safe to stage
//   issue 6 loads (tile kt+1 -> cur^1)
//   vmcnt(6): this wave's tile-kt loads landed
//   B2: ALL waves' tile-kt loads landed                   -> safe to compute
__device__ __forceinline__ void gemm_core_256x128(const u16* __restrict__ A,
                                                  const u16* __restrict__ Bw,
                                                  int bm, int bn,
                                                  u16 (*As)[256 * 64],
                                                  u16 (*Bs)[128 * 64],
                                                  floatx4 acc[4][4]) {
  constexpr int NT = NDIM / 64;     // 48 K-tiles
  const int t = threadIdx.x;        // 0..511
  const int l = t & 63;
  const int w = t >> 6;             // wave 0..7
  const int l15 = l & 15, quad = l >> 4;
  const int wm = (w >> 1) * 64, wn = (w & 1) * 64;

  // staging: thread owns chunk col ch (swizzled), rows rb + 64*i
  const int rb = t >> 3;                      // 0..63
  const int ch = (t & 7) ^ (rb & 7);          // pre-swizzled source chunk
  const u16* aSrc = A  + (long)(bm + rb) * NDIM + ch * 8;
  const u16* bSrc = Bw + (long)(bn + rb) * NDIM + ch * 8;

  // LDS read chunk: cc ^ (row&7), row&7 == l15&7 for all frags
  const int s0 = quad ^ (l15 & 7);

#pragma unroll
  for (int i = 0; i < 4; ++i)
#pragma unroll
    for (int j = 0; j < 4; ++j) acc[i][j] = {0.f, 0.f, 0.f, 0.f};

  auto stage = [&](int kt, int buf) {
    const int k0 = kt * 64;
#pragma unroll
    for (int i = 0; i < 4; ++i)   // A: 256 rows x 8 chunks = 4 per thread
      async_load16(aSrc + (long)i * 64 * NDIM + k0, &As[buf][(i * 512 + t) * 8]);
#pragma unroll
    for (int i = 0; i < 2; ++i)   // B: 128 rows x 8 chunks = 2 per thread
      async_load16(bSrc + (long)i * 64 * NDIM + k0, &Bs[buf][(i * 512 + t) * 8]);
  };

  stage(0, 0);

  for (int kt = 0; kt < NT; ++kt) {
    const int cur = kt & 1;
    __builtin_amdgcn_sched_barrier(0);
    __builtin_amdgcn_s_barrier();            // B1
    __builtin_amdgcn_sched_barrier(0);
    if (kt + 1 < NT) {
      stage(kt + 1, cur ^ 1);
      asm volatile("s_waitcnt vmcnt(6)" ::: "memory");
    } else {
      asm volatile("s_waitcnt vmcnt(0)" ::: "memory");
    }
    __builtin_amdgcn_sched_barrier(0);
    __builtin_amdgcn_s_barrier();            // B2
    __builtin_amdgcn_sched_barrier(0);
#pragma unroll
    for (int kk = 0; kk < 2; ++kk) {
      const int sw = s0 ^ (kk << 2);
      bf16x8 af[4], bfr[4];
#pragma unroll
      for (int i = 0; i < 4; ++i)
        af[i] = *(const bf16x8*)(&As[cur][(wm + i * 16 + l15) * 64 + sw * 8]);
#pragma unroll
      for (int j = 0; j < 4; ++j)
        bfr[j] = *(const bf16x8*)(&Bs[cur][(wn + j * 16 + l15) * 64 + sw * 8]);
      __builtin_amdgcn_s_setprio(1);
#pragma unroll
      for (int i = 0; i < 4; ++i)
#pragma unroll
        for (int j = 0; j < 4; ++j)
          acc[i][j] = __builtin_amdgcn_mfma_f32_16x16x32_bf16(af[i], bfr[j], acc[i][j], 0, 0, 0);
      __builtin_amdgcn_s_setprio(0);
    }
  }
}

// fused Q,K,V projection. 648 blocks (9 M-tiles x 72 N-tiles across q,k,v),
// XCD-swizzled (648 % 8 == 0, chunk 81). q,k -> fp32 (RMSNorm needs fp32);
// v -> bf16 directly (identical rounding point to old vf->f2bf path).
__global__ __launch_bounds__(512, 2) void gemm_qkv(const u16* __restrict__ A,
                                                   const u16* __restrict__ wq,
                                                   const u16* __restrict__ wk,
                                                   const u16* __restrict__ wv,
                                                   const float* __restrict__ bq,
                                                   const float* __restrict__ bk,
                                                   const float* __restrict__ bv,
                                                   float* __restrict__ qf,
                                                   float* __restrict__ kf,
                                                   u16* __restrict__ vbf) {
  __shared__ u16 As[2][256 * 64];   // 64 KB
  __shared__ u16 Bs[2][128 * 64];   // 32 KB
  const int bid = blockIdx.x;
  const int swz = (bid & 7) * 81 + (bid >> 3);
  const int tm = swz / 72;
  const int tn = swz % 72;
  const int sel = tn / 24;                    // 0:q 1:k 2:v
  const int bn = (tn % 24) * 128;
  const int bm = tm * 256;
  const u16* Bw = (sel == 0) ? wq : (sel == 1) ? wk : wv;

  floatx4 acc[4][4];
  gemm_core_256x128(A, Bw, bm, bn, As, Bs, acc);

  const int t = threadIdx.x;
  const int l = t & 63, w = t >> 6;
  const int l15 = l & 15, quad = l >> 4;
  const int wm = (w >> 1) * 64, wn = (w & 1) * 64;
  const float* bias = (sel == 0) ? bq : (sel == 1) ? bk : bv;

  if (sel < 2) {
    float* C = sel ? kf : qf;
#pragma unroll
    for (int i = 0; i < 4; ++i) {
      const int gm = bm + wm + i * 16 + quad * 4;
#pragma unroll
      for (int j = 0; j < 4; ++j) {
        const int gn = bn + wn + j * 16 + l15;
        const float bb = bias[gn];
#pragma unroll
        for (int r = 0; r < 4; ++r)
          C[(long)(gm + r) * NDIM + gn] = acc[i][j][r] + bb;
      }
    }
  } else {
#pragma unroll
    for (int i = 0; i < 4; ++i) {
      const int gm = bm + wm + i * 16 + quad * 4;
#pragma unroll
      for (int j = 0; j < 4; ++j) {
        const int gn = bn + wn + j * 16 + l15;
        const float bb = bias[gn];
#pragma unroll
        for (int r = 0; r < 4; ++r)
          vbf[(long)(gm + r) * NDIM + gn] = f2bf(acc[i][j][r] + bb);
      }
    }
  }
}

// output projection: 216 blocks (9 x 24), all co-resident in one round.
__global__ __launch_bounds__(512, 2) void gemm_bt(const u16* __restrict__ A,
                                                  const u16* __restrict__ Bw,
                                                  const float* __restrict__ bias,
                                                  float* __restrict__ C) {
  __shared__ u16 As[2][256 * 64];
  __shared__ u16 Bs[2][128 * 64];
  const int bid = blockIdx.x;
  const int swz = (bid & 7) * 27 + (bid >> 3);
  const int tm = swz / 24;
  const int tn = swz % 24;
  const int bm = tm * 256;
  const int bn = tn * 128;

  floatx4 acc[4][4];
  gemm_core_256x128(A, Bw, bm, bn, As, Bs, acc);

  const int t = threadIdx.x;
  const int l = t & 63, w = t >> 6;
  const int l15 = l & 15, quad = l >> 4;
  const int wm = (w >> 1) * 64, wn = (w & 1) * 64;
#pragma unroll
  for (int i = 0; i < 4; ++i) {
    const int gm = bm + wm + i * 16 + quad * 4;
#pragma unroll
    for (int j = 0; j < 4; ++j) {
      const int gn = bn + wn + j * 16 + l15;
      const float bb = bias[gn];
#pragma unroll
      for (int r = 0; r < 4; ++r)
        C[(long)(gm + r) * NDIM + gn] = acc[i][j][r] + bb;
    }
  }
}

// --------------------------------------------------- fused RMSNorm + 3D RoPE
// blockIdx.y: 0 -> q, 1 -> k
__global__ __launch_bounds__(256) void rmsnorm_rope(const float* __restrict__ qxf,
                                                    const float* __restrict__ kxf,
                                                    const float* __restrict__ gqp,
                                                    const float* __restrict__ gkp,
                                                    const float* __restrict__ freqs,
                                                    const int* __restrict__ gsz,
                                                    u16* __restrict__ qop,
                                                    u16* __restrict__ kop) {
  const int tok = blockIdx.x;
  const int tid = threadIdx.x;
  const float* xf = blockIdx.y ? kxf : qxf;
  const float* g  = blockIdx.y ? gkp : gqp;
  u16* outp       = blockIdx.y ? kop : qop;
  const float* row = xf + (long)tok * NDIM;
  float4 v[3];
  float ss = 0.f;
#pragma unroll
  for (int p = 0; p < 3; ++p) {
    v[p] = ((const float4*)row)[p * 256 + tid];
    ss += v[p].x * v[p].x + v[p].y * v[p].y + v[p].z * v[p].z + v[p].w * v[p].w;
  }
#pragma unroll
  for (int m = 1; m < 64; m <<= 1) ss += __shfl_xor(ss, m);
  __shared__ float red[4];
  if ((tid & 63) == 0) red[tid >> 6] = ss;
  __syncthreads();
  ss = red[0] + red[1] + red[2] + red[3];
  const float scale = rsqrtf(ss * (1.0f / NDIM) + 1e-6f);

  const int gh = gsz[1], gw = gsz[2];
  const int hw = gh * gw;
  const int fi = tok / hw;
  const int hi = (tok % hw) / gw;
  const int wi = tok % gw;
#pragma unroll
  for (int p = 0; p < 3; ++p) {
    const int e0 = (p * 256 + tid) * 4;
    const float4 gg = ((const float4*)g)[p * 256 + tid];
    const int hh = e0 >> 7;
    const int d = e0 & 127;
    const int c0 = d >> 1;
    int pos0 = (c0 < 22) ? fi : ((c0 < 43) ? hi : wi);
    int pos1 = (c0 + 1 < 22) ? fi : ((c0 + 1 < 43) ? hi : wi);
    float th0 = freqs[pos0 * 64 + c0];
    float th1 = freqs[pos1 * 64 + c0 + 1];
    float s0, cc0, s1, cc1;
    __sincosf(th0, &s0, &cc0);
    __sincosf(th1, &s1, &cc1);
    float x0 = v[p].x * scale * gg.x;
    float x1 = v[p].y * scale * gg.y;
    float x2 = v[p].z * scale * gg.z;
    float x3 = v[p].w * scale * gg.w;
    union { u16 h[4]; uint2 u; } o;
    o.h[0] = f2bf(x0 * cc0 - x1 * s0);
    o.h[1] = f2bf(x0 * s0 + x1 * cc0);
    o.h[2] = f2bf(x2 * cc1 - x3 * s1);
    o.h[3] = f2bf(x2 * s1 + x3 * cc1);
    *(uint2*)(outp + ((long)hh * S_LEN + tok) * HD + d) = o.u;
  }
}

// ----------------------------------------------- V: [S,3072] bf16 -> [3072,S] bf16
__global__ __launch_bounds__(256) void vtrans(const u16* __restrict__ vb,
                                              u16* __restrict__ vt) {
  __shared__ u16 tile[64][66];   // +2 pad: read banks (c + r/2)%32 -> 2-way
  const int c0 = blockIdx.x * 64;
  const int t0 = blockIdx.y * 64;
  const int tid = threadIdx.x;
#pragma unroll
  for (int it = 0; it < 16; ++it) {
    int idx = it * 256 + tid;
    int r = idx >> 6, c = idx & 63;
    tile[r][c] = vb[(long)(t0 + r) * NDIM + c0 + c];
  }
  __syncthreads();
#pragma unroll
  for (int it = 0; it < 16; ++it) {
    int idx = it * 256 + tid;
    int r = idx >> 6, c = idx & 63;
    vt[(long)(c0 + r) * S_LEN + t0 + c] = tile[c][r];
  }
}

// ------------------------------------------------------------ flash attention
// qb,kb: bf16 [NH][S][HD]; vt: bf16 [NH*HD][S]; out: bf16 [S][3072].
// 432 blocks x 256 threads (4 waves x 32 q-rows, Q-tile 128). K-tile = 64,
// double-buffered (prefetch issued right after the single per-iter barrier).
// NO online max: post-RMSNorm |s*SC| <= ~11 so exp is fp32-safe un-shifted;
// row-sum l comes from an MFMA with an all-ones B operand (every column of
// P @ ones holds the row sum, already in per-lane C-layout -> no shuffles,
// no rescale of O). LDS = 2*16(K)+2*16(V)+16(P) = 80 KB -> 2 blocks/CU.
// XCD swizzle: b&7 -> xcd, 3 heads x 18 qtiles per XCD (K+V fits 4MB L2).
__global__ __launch_bounds__(256, 2) void attn_kern(const u16* __restrict__ qb,
                                                    const u16* __restrict__ kb,
                                                    const u16* __restrict__ vt,
                                                    const int* __restrict__ seq_lens,
                                                    u16* __restrict__ ob) {
  __shared__ u16 Kb[2][64 * 128];   // K tile: 64 tok rows x 16 chunks, swz 15
  __shared__ u16 Vb[2][128 * 64];   // V^T tile: 128 d rows x 8 chunks, swz 7
  __shared__ u16 Ps[128 * 64];      // P tile: 128 q rows x 8 chunks, swz 7
  const int b = blockIdx.x;           // 0..431
  const int xcd = b & 7;
  const int slot = b >> 3;            // 0..53
  const int h = xcd * 3 + slot / 18;  // 3 heads per XCD
  const int qt = slot % 18;
  const int t = threadIdx.x;
  const int l = t & 63, w = t >> 6;
  const int l15 = l & 15, quad = l >> 4;
  const int seqlen = seq_lens[0];
  const float SC2 = 0.12753102543f;   // (1/sqrt(128)) * log2(e), for exp2f

  const u16* kbase = kb + (long)h * S_LEN * HD;
  const u16* vbase = vt + (long)h * HD * S_LEN;

  // Q fragments: A-layout m = lane&15, k = quad*8 + j
  bf16x8 qfrag[2][4];
#pragma unroll
  for (int i = 0; i < 2; ++i) {
    const u16* qrow = qb + ((long)h * S_LEN + qt * 128 + w * 32 + i * 16 + l15) * HD + quad * 8;
#pragma unroll
    for (int kk = 0; kk < 4; ++kk) qfrag[i][kk] = *(const bf16x8*)(qrow + kk * 32);
  }

  bf16x8 ones;
#pragma unroll
  for (int i = 0; i < 8; ++i) ones[i] = (__bf16)1.0f;

  floatx4 oacc[2][8];
  floatx4 lacc[2];
#pragma unroll
  for (int i = 0; i < 2; ++i) {
#pragma unroll
    for (int j = 0; j < 8; ++j) oacc[i][j] = {0.f, 0.f, 0.f, 0.f};
    lacc[i] = {0.f, 0.f, 0.f, 0.f};
  }

  // stage K-tile (64x128) + V-tile (128x64) for tile `kt` into buffer `buf`
  auto stage = [&](int kt, int buf) {
#pragma unroll
    for (int i = 0; i < 4; ++i) {
      int p = i * 256 + t;              // 0..1023
      int rk = p >> 4;                  // K: token row 0..63
      int ck = (p & 15) ^ (rk & 15);
      async_load16(kbase + ((long)(kt * 64 + rk)) * HD + ck * 8, &Kb[buf][p * 8]);
      int dv = p >> 3;                  // V: hd row 0..127
      int cv = (p & 7) ^ (dv & 7);
      async_load16(vbase + (long)dv * S_LEN + kt * 64 + cv * 8, &Vb[buf][p * 8]);
    }
  };

  stage(0, 0);

  for (int kt = 0; kt < S_LEN / 64; ++kt) {
    const int cur = kt & 1;
    __syncthreads();                   // tile kt loads done; prev compute done
    if (kt + 1 < S_LEN / 64) stage(kt + 1, cur ^ 1);

    // S = Q K^T  (128q x 64k)
    floatx4 sacc[2][4];
#pragma unroll
    for (int i = 0; i < 2; ++i)
#pragma unroll
      for (int j = 0; j < 4; ++j) sacc[i][j] = {0.f, 0.f, 0.f, 0.f};
#pragma unroll
    for (int kk = 0; kk < 4; ++kk) {
#pragma unroll
      for (int j = 0; j < 4; ++j) {
        int row = j * 16 + l15;
        int cc = kk * 4 + quad;
        bf16x8 bk = *(const bf16x8*)(&Kb[cur][(row * 16 + (cc ^ (row & 15))) * 8]);
        sacc[0][j] = __builtin_amdgcn_mfma_f32_16x16x32_bf16(qfrag[0][kk], bk, sacc[0][j], 0, 0, 0);
        sacc[1][j] = __builtin_amdgcn_mfma_f32_16x16x32_bf16(qfrag[1][kk], bk, sacc[1][j], 0, 0, 0);
      }
    }

    // unshifted softmax numerator: p = 2^(s*SC2)  (masked cols -> 0)
    const bool tail = (kt * 64 + 64 > seqlen);
#pragma unroll
    for (int i = 0; i < 2; ++i)
#pragma unroll
      for (int j = 0; j < 4; ++j)
#pragma unroll
        for (int r = 0; r < 4; ++r) {
          float sv = sacc[i][j][r] * SC2;
          if (tail) {
            int col = kt * 64 + j * 16 + l15;
            if (col >= seqlen) sv = -1e30f;
          }
          sacc[i][j][r] = exp2f(sv);
        }

    // write P into its own buffer (wave-private rows -> no barrier)
#pragma unroll
    for (int i = 0; i < 2; ++i)
#pragma unroll
      for (int j = 0; j < 4; ++j)
#pragma unroll
        for (int r = 0; r < 4; ++r) {
          int rq = w * 32 + i * 16 + quad * 4 + r;   // 0..127
          int ct = j * 16 + l15;                     // 0..63
          int cc = ct >> 3;
          Ps[(rq * 8 + (cc ^ (rq & 7))) * 8 + (ct & 7)] = f2bf(sacc[i][j][r]);
        }

    // O += P V ; l += P @ ones  (A-frags: own rows of Ps)
#pragma unroll
    for (int kl = 0; kl < 2; ++kl) {
      bf16x8 ap[2];
#pragma unroll
      for (int i = 0; i < 2; ++i) {
        int row = w * 32 + i * 16 + l15;
        int cc = kl * 4 + quad;
        ap[i] = *(const bf16x8*)(&Ps[(row * 8 + (cc ^ (row & 7))) * 8]);
      }
      lacc[0] = __builtin_amdgcn_mfma_f32_16x16x32_bf16(ap[0], ones, lacc[0], 0, 0, 0);
      lacc[1] = __builtin_amdgcn_mfma_f32_16x16x32_bf16(ap[1], ones, lacc[1], 0, 0, 0);
#pragma unroll
      for (int j = 0; j < 8; ++j) {
        int d = j * 16 + l15;
        int ccv = kl * 4 + quad;
        bf16x8 bv = *(const bf16x8*)(&Vb[cur][(d * 8 + (ccv ^ (d & 7))) * 8]);
        oacc[0][j] = __builtin_amdgcn_mfma_f32_16x16x32_bf16(ap[0], bv, oacc[0][j], 0, 0, 0);
        oacc[1][j] = __builtin_amdgcn_mfma_f32_16x16x32_bf16(ap[1], bv, oacc[1][j], 0, 0, 0);
      }
    }
  }

  // epilogue: out[t][h*128+d] = O / l
#pragma unroll
  for (int i = 0; i < 2; ++i) {
    float inv[4];
#pragma unroll
    for (int r = 0; r < 4; ++r) inv[r] = 1.0f / lacc[i][r];
#pragma unroll
    for (int j = 0; j < 8; ++j) {
      int gt = qt * 128 + w * 32 + i * 16 + quad * 4;
      int gc = h * HD + j * 16 + l15;
#pragma unroll
      for (int r = 0; r < 4; ++r)
        ob[(long)(gt + r) * NDIM + gc] = f2bf(oacc[i][j][r] * inv[r]);
    }
  }
}

// ----------------------------------------------------------------------------
extern "C" void kernel_launch(void* const* d_in, const int* in_sizes, int n_in,
                              void* d_out, int out_size, void* d_ws, size_t ws_size,
                              hipStream_t stream) {
  const float* x        = (const float*)d_in[0];
  const int*   seq_lens = (const int*)  d_in[1];
  const int*   gsz      = (const int*)  d_in[2];
  const float* freqs    = (const float*)d_in[3];
  const float* wq       = (const float*)d_in[4];
  const float* bq       = (const float*)d_in[5];
  const float* wk       = (const float*)d_in[6];
  const float* bk       = (const float*)d_in[7];
  const float* wv       = (const float*)d_in[8];
  const float* bv       = (const float*)d_in[9];
  const float* wo       = (const float*)d_in[10];
  const float* bo       = (const float*)d_in[11];
  const float* gq       = (const float*)d_in[12];
  const float* gk       = (const float*)d_in[13];
  float* out = (float*)d_out;

  char* ws = (char*)d_ws;
  const size_t SD2 = (size_t)S_LEN * NDIM * 2;   // bf16 [S,3072]
  const size_t W2  = (size_t)NDIM * NDIM * 2;    // bf16 [3072,3072]
  const size_t SD4 = (size_t)S_LEN * NDIM * 4;   // fp32 [S,3072]
  size_t off = 0;
  u16* xb    = (u16*)(ws + off); off += SD2;
  u16* wqb   = (u16*)(ws + off); off += W2;
  u16* wkb   = (u16*)(ws + off); off += W2;
  u16* wvb   = (u16*)(ws + off); off += W2;
  u16* wob   = (u16*)(ws + off); off += W2;
  float* qf  = (float*)(ws + off); off += SD4;
  float* kf  = (float*)(ws + off); off += SD4;
  u16* vbf   = (u16*)(ws + off); off += SD4;    // slot kept fp32-sized; holds bf16
  u16* qbuf  = (u16*)(ws + off); off += SD2;
  u16* kbuf  = (u16*)(ws + off); off += SD2;
  u16* vtb   = (u16*)(ws + off); off += SD2;
  u16* attnb = (u16*)(ws + off); off += SD2;

  cvt_all<<<3456 + 4 * 4608, 256, 0, stream>>>(x, wq, wk, wv, wo,
                                               xb, wqb, wkb, wvb, wob);

  gemm_qkv<<<648, 512, 0, stream>>>(xb, wqb, wkb, wvb,
                                    bq, bk, bv, qf, kf, vbf);

  rmsnorm_rope<<<dim3(S_LEN, 2), 256, 0, stream>>>(qf, kf, gq, gk, freqs, gsz,
                                                   qbuf, kbuf);
  vtrans<<<dim3(NDIM / 64, S_LEN / 64), 256, 0, stream>>>(vbf, vtb);

  attn_kern<<<432, 256, 0, stream>>>(qbuf, kbuf, vtb, seq_lens, attnb);

  gemm_bt<<<216, 512, 0, stream>>>(attnb, wob, bo, out);
}